// Round 11
// baseline (341.166 us; speedup 1.0000x reference)
//
#include <hip/hip_runtime.h>
#include <math.h>

#define N_NODES 2000
#define NA 16
#define NOBS 64
#define NH 128
#define NE 16000
#define NITERS 8

// ---------------- workspace layout (float offsets) ----------------
#define WS_MSG       0                       // 2E*16 = 512000
#define WS_Q         512000                  // 8
#define WS_ZERO_CNT  512008                  // msg + q zeroed in setup
#define WS_SBUF      512016                  // 9 x 32000 uS buffers (u-initialized by umlp)
#define WS_AIDX      800016                  // int[8*2000]
#define WS_W         816016                  // int[16000] wflag
#define WS_PT        832016                  // pT 4,096,000; owner map (4,000,000 ints) aliases
#define WS_GIT       (WS_PT + 4000000)       // gru wihT k-panel 80x384 = 30720 (dead after gru)
#define WS_GHT       (WS_GIT + 30720)        // gru whhT k-panel 128x384 = 49152 (ends < WS_WB)
#define WS_WB        4928016                 // transposed weights base (contiguous chain)
#define WS_UW0T      (WS_WB + 0)             // 128x256
#define WS_UWCAT     (WS_WB + 32768)         // 128x256  [W0a@h | W0b@h] combined
#define WS_UW1T      (WS_WB + 65536)         // 256x256
#define WS_UW2T      (WS_WB + 131072)        // 256x16
#define WS_PW1T      (WS_WB + 135168)        // 128x256
#define WS_PW2T      (WS_WB + 167936)        // 256x256
#define WS_PW3T      (WS_WB + 233472)        // 256x16
#define WS_PW4T      (WS_WB + 237568)        // 16x256
#define WS_CAB       (WS_WB + 241664)        // cab[2000][256] = 512000
// end: 5,681,680 floats (~22.7 MB)
// NOTE: weight ping-pong prefetch reads up to ~2K floats past an array's
// end — always lands in the NEXT array in the chain (benign; last array
// PW4T is only used by L4 which has no ping-pong overreach).

// ---------------- setup: zero msg/q, transpose weights ----------------------
__global__ __launch_bounds__(256) void setup_kernel(
    float* __restrict__ ws,
    const float* __restrict__ uW0, const float* __restrict__ uW1,
    const float* __restrict__ uW2, const float* __restrict__ pW0,
    const float* __restrict__ pW1, const float* __restrict__ pW2,
    const float* __restrict__ pW3, const float* __restrict__ pW4,
    const float* __restrict__ gwih, const float* __restrict__ gwhh)
{
    const int total = WS_ZERO_CNT + 321536;
    for (int idx = blockIdx.x * 256 + threadIdx.x; idx < total;
         idx += gridDim.x * 256) {
        if (idx < WS_ZERO_CNT) {
            ws[idx] = 0.f;
        } else {
            int t = idx - WS_ZERO_CNT;
            if (t < 241664) {
                float v;
                if (t < 32768) {
                    int k = t / 256, o = t % 256;           // uW0T
                    v = uW0[o * 128 + k];
                } else if (t < 65536) {
                    int q = t - 32768, k = q / 256, o = q % 256;  // UWCAT: split pW0
                    v = (o < 128) ? pW0[o * 256 + k]
                                  : pW0[(o - 128) * 256 + 128 + k];
                } else if (t < 131072) {
                    int q = t - 65536, k = q / 256, o = q % 256;  // uW1T
                    v = uW1[o * 256 + k];
                } else if (t < 135168) {
                    int q = t - 131072, k = q / 16, o = q % 16;   // uW2T
                    v = uW2[o * 256 + k];
                } else if (t < 167936) {
                    int q = t - 135168, k = q / 256, o = q % 256; // pW1T
                    v = pW1[o * 128 + k];
                } else if (t < 233472) {
                    int q = t - 167936, k = q / 256, o = q % 256; // pW2T
                    v = pW2[o * 256 + k];
                } else if (t < 237568) {
                    int q = t - 233472, k = q / 16, o = q % 16;   // pW3T
                    v = pW3[o * 256 + k];
                } else {
                    int q = t - 237568, k = q / 256, o = q % 256; // pW4T
                    v = pW4[o * 16 + k];
                }
                ws[WS_WB + t] = v;
            } else if (t < 272384) {
                int q = t - 241664;   // gru wihT k-panel
                int k4 = q / 1536, r = q % 1536, g = r >> 2, c = r & 3;
                ws[WS_GIT + q] = gwih[g * 80 + 4 * k4 + c];
            } else {
                int q = t - 272384;
                int k4 = q / 1536, r = q % 1536, g = r >> 2, c = r & 3;
                ws[WS_GHT + q] = gwhh[g * 128 + 4 * k4 + c];
            }
        }
    }
}

// ---------------- dedup: init touched owner slots, claim, resolve -----------
__global__ __launch_bounds__(256) void init_owner_kernel(
    const int* __restrict__ edges, int* __restrict__ owner)
{
    int e = blockIdx.x * 256 + threadIdx.x;
    if (e < NE) {
        int i = edges[2 * e], j = edges[2 * e + 1];
        owner[i * N_NODES + j] = -1;
    }
}

__global__ __launch_bounds__(256) void claim_kernel(
    const int* __restrict__ edges, int* __restrict__ owner)
{
    int e = blockIdx.x * 256 + threadIdx.x;
    if (e < NE) {
        int i = edges[2 * e], j = edges[2 * e + 1];
        atomicMax(&owner[i * N_NODES + j], e);
    }
}

__global__ __launch_bounds__(256) void resolve_kernel(
    const int* __restrict__ edges, const int* __restrict__ owner,
    int* __restrict__ wflag)
{
    int e = blockIdx.x * 256 + threadIdx.x;
    if (e < NE) {
        int i = edges[2 * e], j = edges[2 * e + 1];
        wflag[e] = (owner[i * N_NODES + j] == e) ? 1 : 0;
    }
}

// ---------------- GRU encoder -------------------------------------------------
__global__ __launch_bounds__(256) void gru_kernel(
    const float* __restrict__ x, const float* __restrict__ pa,
    const float* __restrict__ st, const float* __restrict__ wihT,
    const float* __restrict__ whhT, const float* __restrict__ bih,
    const float* __restrict__ bhh, float* __restrict__ h_out)
{
    __shared__ float enc[8][80];
    __shared__ float hp[8][128];
    __shared__ float gi[8][384];
    __shared__ float gh[8][384];
    const int tid = threadIdx.x;
    const int n0 = blockIdx.x * 8;

    for (int idx = tid; idx < 8 * 80; idx += 256) {
        int r = idx / 80, c = idx % 80;
        enc[r][c] = (c < 64) ? x[(n0 + r) * 64 + c] : pa[(n0 + r) * 16 + (c - 64)];
    }
    for (int idx = tid; idx < 8 * 128; idx += 256) {
        int r = idx >> 7, c = idx & 127;
        hp[r][c] = st[(n0 + r) * 128 + c];
    }
    __syncthreads();

    for (int idx = tid; idx < 8 * 384; idx += 256) {
        int g = idx % 384, r = idx / 384;
        float s1 = bih[g];
        #pragma unroll 5
        for (int k4 = 0; k4 < 20; ++k4) {
            const float4 ev = *(const float4*)&enc[r][4 * k4];
            const float4 wv = *(const float4*)&wihT[k4 * 1536 + g * 4];
            s1 = fmaf(ev.x, wv.x, fmaf(ev.y, wv.y, fmaf(ev.z, wv.z, fmaf(ev.w, wv.w, s1))));
        }
        gi[r][g] = s1;
        float s2 = bhh[g];
        #pragma unroll 8
        for (int k4 = 0; k4 < 32; ++k4) {
            const float4 hv = *(const float4*)&hp[r][4 * k4];
            const float4 wv = *(const float4*)&whhT[k4 * 1536 + g * 4];
            s2 = fmaf(hv.x, wv.x, fmaf(hv.y, wv.y, fmaf(hv.z, wv.z, fmaf(hv.w, wv.w, s2))));
        }
        gh[r][g] = s2;
    }
    __syncthreads();

    for (int idx = tid; idx < 8 * 128; idx += 256) {
        int r = idx >> 7, c = idx & 127;
        float rr = 1.f / (1.f + expf(-(gi[r][c] + gh[r][c])));
        float zz = 1.f / (1.f + expf(-(gi[r][128 + c] + gh[r][128 + c])));
        float nn = tanhf(gi[r][256 + c] + rr * gh[r][256 + c]);
        h_out[(n0 + r) * 128 + c] = (1.f - zz) * nn + zz * hp[r][c];
    }
}

// ---------------- u MLP + per-node p-L0 precompute ---------------------------
// blocks 0..249:   u MLP 128->256->256->16, /N; u_out + 9 uS slots (S starts 0)
// blocks 250..499: cab[n] = [W0a@h_n | W0b@h_n]  (p-MLP L0 decomposition;
//                  no bias/relu — added per-edge in pmlp staging)
__global__ __launch_bounds__(256) void umlp_kernel(
    const float* __restrict__ h, const float* __restrict__ w0t,
    const float* __restrict__ b0, const float* __restrict__ w1t,
    const float* __restrict__ b1, const float* __restrict__ w2t,
    const float* __restrict__ b2, const float* __restrict__ wcat,
    float* __restrict__ u_out, float* __restrict__ Sbuf,
    float* __restrict__ cab)
{
    __shared__ float A[8][128];
    __shared__ float B[8][256];
    const int tid = threadIdx.x;
    const bool is_cab = blockIdx.x >= 250;
    const int n0 = (is_cab ? blockIdx.x - 250 : blockIdx.x) * 8;

    for (int idx = tid; idx < 8 * 128; idx += 256) {
        int r = idx >> 7, c = idx & 127;
        A[r][c] = h[(n0 + r) * 128 + c];
    }
    __syncthreads();

    if (is_cab) {
        // 128->256, no bias/relu, ping-pong weights
        const int o = tid;
        const float* wp = wcat + o;
        float wA[4], wB[4];
        #pragma unroll
        for (int c = 0; c < 4; ++c) wA[c] = wp[c * 256];
        float acc[8];
        #pragma unroll
        for (int r = 0; r < 8; ++r) acc[r] = 0.f;
        for (int k4 = 0; k4 < 32; k4 += 2) {
            #pragma unroll
            for (int c = 0; c < 4; ++c) wB[c] = wp[(4 * (k4 + 1) + c) * 256];
            #pragma unroll
            for (int r = 0; r < 8; ++r) {
                const float4 av = *(const float4*)&A[r][4 * k4];
                acc[r] = fmaf(av.x, wA[0], fmaf(av.y, wA[1], fmaf(av.z, wA[2], fmaf(av.w, wA[3], acc[r]))));
            }
            #pragma unroll
            for (int c = 0; c < 4; ++c) wA[c] = wp[(4 * (k4 + 2) + c) * 256]; // benign OOB at last pair
            #pragma unroll
            for (int r = 0; r < 8; ++r) {
                const float4 av = *(const float4*)&A[r][4 * k4 + 4];
                acc[r] = fmaf(av.x, wB[0], fmaf(av.y, wB[1], fmaf(av.z, wB[2], fmaf(av.w, wB[3], acc[r]))));
            }
        }
        #pragma unroll
        for (int r = 0; r < 8; ++r) cab[(n0 + r) * 256 + o] = acc[r];
        return;
    }

    // L0: 128->256 relu, A->B
    {
        const int o = tid;
        const float* wp = w0t + o;
        float wA[4], wB[4];
        #pragma unroll
        for (int c = 0; c < 4; ++c) wA[c] = wp[c * 256];
        float acc[8];
        #pragma unroll
        for (int r = 0; r < 8; ++r) acc[r] = b0[o];
        for (int k4 = 0; k4 < 32; k4 += 2) {
            #pragma unroll
            for (int c = 0; c < 4; ++c) wB[c] = wp[(4 * (k4 + 1) + c) * 256];
            #pragma unroll
            for (int r = 0; r < 8; ++r) {
                const float4 av = *(const float4*)&A[r][4 * k4];
                acc[r] = fmaf(av.x, wA[0], fmaf(av.y, wA[1], fmaf(av.z, wA[2], fmaf(av.w, wA[3], acc[r]))));
            }
            #pragma unroll
            for (int c = 0; c < 4; ++c) wA[c] = wp[(4 * (k4 + 2) + c) * 256]; // benign OOB at last pair
            #pragma unroll
            for (int r = 0; r < 8; ++r) {
                const float4 av = *(const float4*)&A[r][4 * k4 + 4];
                acc[r] = fmaf(av.x, wB[0], fmaf(av.y, wB[1], fmaf(av.z, wB[2], fmaf(av.w, wB[3], acc[r]))));
            }
        }
        #pragma unroll
        for (int r = 0; r < 8; ++r) B[r][o] = fmaxf(acc[r], 0.f);
    }
    __syncthreads();
    // L1: 256->256 relu, B->B (register staged)
    {
        const int o = tid;
        const float* wp = w1t + o;
        float wA[4], wB[4];
        #pragma unroll
        for (int c = 0; c < 4; ++c) wA[c] = wp[c * 256];
        float acc[8];
        #pragma unroll
        for (int r = 0; r < 8; ++r) acc[r] = b1[o];
        for (int k4 = 0; k4 < 64; k4 += 2) {
            #pragma unroll
            for (int c = 0; c < 4; ++c) wB[c] = wp[(4 * (k4 + 1) + c) * 256];
            #pragma unroll
            for (int r = 0; r < 8; ++r) {
                const float4 av = *(const float4*)&B[r][4 * k4];
                acc[r] = fmaf(av.x, wA[0], fmaf(av.y, wA[1], fmaf(av.z, wA[2], fmaf(av.w, wA[3], acc[r]))));
            }
            #pragma unroll
            for (int c = 0; c < 4; ++c) wA[c] = wp[(4 * (k4 + 2) + c) * 256]; // benign OOB at last pair
            #pragma unroll
            for (int r = 0; r < 8; ++r) {
                const float4 av = *(const float4*)&B[r][4 * k4 + 4];
                acc[r] = fmaf(av.x, wB[0], fmaf(av.y, wB[1], fmaf(av.z, wB[2], fmaf(av.w, wB[3], acc[r]))));
            }
        }
        __syncthreads();
        #pragma unroll
        for (int r = 0; r < 8; ++r) B[r][o] = fmaxf(acc[r], 0.f);
    }
    __syncthreads();
    // L2: 256->16, /N, no relu (threads 0..127); fan out to u and 9 uS slots
    if (tid < 128) {
        int r = tid >> 4, o = tid & 15;
        float acc = b2[o];
        for (int k4 = 0; k4 < 64; ++k4) {
            const float4 av = *(const float4*)&B[r][4 * k4];
            acc = fmaf(av.x, w2t[(4 * k4 + 0) * 16 + o],
                  fmaf(av.y, w2t[(4 * k4 + 1) * 16 + o],
                  fmaf(av.z, w2t[(4 * k4 + 2) * 16 + o],
                  fmaf(av.w, w2t[(4 * k4 + 3) * 16 + o], acc))));
        }
        float val = acc * (1.f / N_NODES);
        int idx = (n0 + r) * 16 + o;
        u_out[idx] = val;
        #pragma unroll
        for (int t = 0; t < NITERS + 1; ++t) Sbuf[t * 32000 + idx] = val;
    }
}

// ---------------- p MLP: L0 collapsed to cab gather + add --------------------
// 32 rows (16 edges)/block, single LDS buffer (35 KB, 4 blocks/CU).
// L0 per edge-dir = relu(ca_first + cb_second + b0) — computed during staging.
__global__ __launch_bounds__(256, 4) void pmlp_kernel(
    const float* __restrict__ cab, const int* __restrict__ edges,
    const float* __restrict__ b0,
    const float* __restrict__ w1t, const float* __restrict__ b1,
    const float* __restrict__ w2t, const float* __restrict__ b2,
    const float* __restrict__ w3t, const float* __restrict__ b3,
    const float* __restrict__ w4t, const float* __restrict__ b4,
    float* __restrict__ p_out, float* __restrict__ pT)
{
    __shared__ float A[32][256];   // 32 KB — the only activation buffer
    __shared__ float C16[32][16];  // 2 KB
    __shared__ int fi[32], se[32];
    const int tid = threadIdx.x;
    const int e0 = blockIdx.x * 16;
    const int rg = tid >> 6;       // wave id = row group
    const int ct = tid & 63;
    const int r0 = rg * 8;

    if (tid < 16) {
        int i = edges[2 * (e0 + tid)], j = edges[2 * (e0 + tid) + 1];
        fi[2 * tid] = i;     se[2 * tid] = j;       // row 2s  = dir (i,j)
        fi[2 * tid + 1] = j; se[2 * tid + 1] = i;   // row 2s+1 = dir (j,i)
    }
    __syncthreads();
    // L0 (collapsed): A[r][0..127] = relu(ca[fi] + cb[se] + b0)
    {
        const int cl = tid & 127;
        const int rh = tid >> 7;   // 0 or 1: rows 0-15 / 16-31
        const float bb = b0[cl];
        #pragma unroll 4
        for (int r = rh * 16; r < rh * 16 + 16; ++r) {
            float v = cab[fi[r] * 256 + cl] + cab[se[r] * 256 + 128 + cl] + bb;
            A[r][cl] = fmaxf(v, 0.f);
        }
    }
    __syncthreads();
    // L1: 128->256 relu. Reads A[r][0..127], writes A[r][0..255] (4 cols/thr).
    // Rows wave-private from here; loads precede stores in wave program order.
    {
        const float4* wp = (const float4*)w1t + ct;
        float4 wA[4], wB[4];
        #pragma unroll
        for (int c = 0; c < 4; ++c) wA[c] = wp[c * 64];
        float4 bb = ((const float4*)b1)[ct];
        float acc[8][4];
        #pragma unroll
        for (int r = 0; r < 8; ++r) {
            acc[r][0] = bb.x; acc[r][1] = bb.y; acc[r][2] = bb.z; acc[r][3] = bb.w;
        }
        for (int k4 = 0; k4 < 32; k4 += 2) {
            #pragma unroll
            for (int c = 0; c < 4; ++c) wB[c] = wp[(4 * (k4 + 1) + c) * 64];
            #pragma unroll
            for (int r = 0; r < 8; ++r) {
                const float4 av = *(const float4*)&A[r0 + r][4 * k4];
                acc[r][0] = fmaf(av.x, wA[0].x, fmaf(av.y, wA[1].x, fmaf(av.z, wA[2].x, fmaf(av.w, wA[3].x, acc[r][0]))));
                acc[r][1] = fmaf(av.x, wA[0].y, fmaf(av.y, wA[1].y, fmaf(av.z, wA[2].y, fmaf(av.w, wA[3].y, acc[r][1]))));
                acc[r][2] = fmaf(av.x, wA[0].z, fmaf(av.y, wA[1].z, fmaf(av.z, wA[2].z, fmaf(av.w, wA[3].z, acc[r][2]))));
                acc[r][3] = fmaf(av.x, wA[0].w, fmaf(av.y, wA[1].w, fmaf(av.z, wA[2].w, fmaf(av.w, wA[3].w, acc[r][3]))));
            }
            #pragma unroll
            for (int c = 0; c < 4; ++c) wA[c] = wp[(4 * (k4 + 2) + c) * 64]; // benign OOB at last pair
            #pragma unroll
            for (int r = 0; r < 8; ++r) {
                const float4 av = *(const float4*)&A[r0 + r][4 * k4 + 4];
                acc[r][0] = fmaf(av.x, wB[0].x, fmaf(av.y, wB[1].x, fmaf(av.z, wB[2].x, fmaf(av.w, wB[3].x, acc[r][0]))));
                acc[r][1] = fmaf(av.x, wB[0].y, fmaf(av.y, wB[1].y, fmaf(av.z, wB[2].y, fmaf(av.w, wB[3].y, acc[r][1]))));
                acc[r][2] = fmaf(av.x, wB[0].z, fmaf(av.y, wB[1].z, fmaf(av.z, wB[2].z, fmaf(av.w, wB[3].z, acc[r][2]))));
                acc[r][3] = fmaf(av.x, wB[0].w, fmaf(av.y, wB[1].w, fmaf(av.z, wB[2].w, fmaf(av.w, wB[3].w, acc[r][3]))));
            }
        }
        #pragma unroll
        for (int r = 0; r < 8; ++r) {
            float4 v = make_float4(fmaxf(acc[r][0], 0.f), fmaxf(acc[r][1], 0.f),
                                   fmaxf(acc[r][2], 0.f), fmaxf(acc[r][3], 0.f));
            *(float4*)&A[r0 + r][4 * ct] = v;
        }
    }
    // no __syncthreads — rows wave-private
    // L2: 256->256 relu, in place (4 cols/thread).
    {
        const float4* wp = (const float4*)w2t + ct;
        float4 wA[4], wB[4];
        #pragma unroll
        for (int c = 0; c < 4; ++c) wA[c] = wp[c * 64];
        float4 bb = ((const float4*)b2)[ct];
        float acc[8][4];
        #pragma unroll
        for (int r = 0; r < 8; ++r) {
            acc[r][0] = bb.x; acc[r][1] = bb.y; acc[r][2] = bb.z; acc[r][3] = bb.w;
        }
        for (int k4 = 0; k4 < 64; k4 += 2) {
            #pragma unroll
            for (int c = 0; c < 4; ++c) wB[c] = wp[(4 * (k4 + 1) + c) * 64];
            #pragma unroll
            for (int r = 0; r < 8; ++r) {
                const float4 av = *(const float4*)&A[r0 + r][4 * k4];
                acc[r][0] = fmaf(av.x, wA[0].x, fmaf(av.y, wA[1].x, fmaf(av.z, wA[2].x, fmaf(av.w, wA[3].x, acc[r][0]))));
                acc[r][1] = fmaf(av.x, wA[0].y, fmaf(av.y, wA[1].y, fmaf(av.z, wA[2].y, fmaf(av.w, wA[3].y, acc[r][1]))));
                acc[r][2] = fmaf(av.x, wA[0].z, fmaf(av.y, wA[1].z, fmaf(av.z, wA[2].z, fmaf(av.w, wA[3].z, acc[r][2]))));
                acc[r][3] = fmaf(av.x, wA[0].w, fmaf(av.y, wA[1].w, fmaf(av.z, wA[2].w, fmaf(av.w, wA[3].w, acc[r][3]))));
            }
            #pragma unroll
            for (int c = 0; c < 4; ++c) wA[c] = wp[(4 * (k4 + 2) + c) * 64]; // benign OOB at last pair
            #pragma unroll
            for (int r = 0; r < 8; ++r) {
                const float4 av = *(const float4*)&A[r0 + r][4 * k4 + 4];
                acc[r][0] = fmaf(av.x, wB[0].x, fmaf(av.y, wB[1].x, fmaf(av.z, wB[2].x, fmaf(av.w, wB[3].x, acc[r][0]))));
                acc[r][1] = fmaf(av.x, wB[0].y, fmaf(av.y, wB[1].y, fmaf(av.z, wB[2].y, fmaf(av.w, wB[3].y, acc[r][1]))));
                acc[r][2] = fmaf(av.x, wB[0].z, fmaf(av.y, wB[1].z, fmaf(av.z, wB[2].z, fmaf(av.w, wB[3].z, acc[r][2]))));
                acc[r][3] = fmaf(av.x, wB[0].w, fmaf(av.y, wB[1].w, fmaf(av.z, wB[2].w, fmaf(av.w, wB[3].w, acc[r][3]))));
            }
        }
        #pragma unroll
        for (int r = 0; r < 8; ++r) {
            float4 v = make_float4(fmaxf(acc[r][0], 0.f), fmaxf(acc[r][1], 0.f),
                                   fmaxf(acc[r][2], 0.f), fmaxf(acc[r][3], 0.f));
            *(float4*)&A[r0 + r][4 * ct] = v;
        }
    }
    __syncthreads();   // L3 crosses waves
    // L3: 256->16 relu, A->C16   (512 tasks)
    for (int idx = tid; idx < 512; idx += 256) {
        int r = idx >> 4, o = idx & 15;
        float acc = b3[o];
        for (int k4 = 0; k4 < 64; ++k4) {
            const float4 av = *(const float4*)&A[r][4 * k4];
            acc = fmaf(av.x, w3t[(4 * k4 + 0) * 16 + o],
                  fmaf(av.y, w3t[(4 * k4 + 1) * 16 + o],
                  fmaf(av.z, w3t[(4 * k4 + 2) * 16 + o],
                  fmaf(av.w, w3t[(4 * k4 + 3) * 16 + o], acc))));
        }
        C16[r][o] = fmaxf(acc, 0.f);
    }
    __syncthreads();
    // L4: 16->256 (no relu), combine dirs, /E ; write p and pT
    {
        int o = tid;
        int ai = o >> 4, aj = o & 15;
        float acc[32];
        #pragma unroll
        for (int r = 0; r < 32; ++r) acc[r] = b4[o];
        #pragma unroll
        for (int k4 = 0; k4 < 4; ++k4) {
            float w0v = w4t[(4 * k4 + 0) * 256 + o];
            float w1v = w4t[(4 * k4 + 1) * 256 + o];
            float w2v = w4t[(4 * k4 + 2) * 256 + o];
            float w3v = w4t[(4 * k4 + 3) * 256 + o];
            #pragma unroll
            for (int r = 0; r < 32; ++r) {
                const float4 av = *(const float4*)&C16[r][4 * k4];
                acc[r] = fmaf(av.x, w0v, fmaf(av.y, w1v, fmaf(av.z, w2v, fmaf(av.w, w3v, acc[r]))));
            }
        }
        #pragma unroll
        for (int s = 0; s < 16; ++s) {
            float v = 0.5f * (acc[2 * s] + acc[2 * s + 1]) * (1.f / NE);
            p_out[(e0 + s) * 256 + o] = v;
            pT[(e0 + s) * 256 + aj * 16 + ai] = v;   // pT[e][aj][ai]
        }
    }
}

// ---------------- merged MP iteration kernel (round-7 structure) -------------
// XCD-aware edge-block swizzle: with the XCD ~= blockIdx.x % 8 placement
// heuristic, block b handles edge-chunk (b&7)*125 + (b>>3), so each XCD
// processes the SAME contiguous 2000-edge slice (2.05 MB of pT — fits its
// 4 MB L2) in every one of the 8 launches -> pT becomes L2-resident per XCD
// after iter 0. Bijection on [0,1000); correctness is mapping-independent.
__global__ __launch_bounds__(256) void mp_iter_kernel(
    const float* __restrict__ u, float* __restrict__ Sbuf,
    float* __restrict__ msg, const float* __restrict__ pT,
    const float* __restrict__ p, const int* __restrict__ edges,
    const int* __restrict__ wflag, int* __restrict__ aidx,
    float* __restrict__ q, int t)
{
    const int tid = threadIdx.x;
    if (blockIdx.x < 1000) {
        // ---- edge phase, iter t ----
        const int b = blockIdx.x;
        const int chunk = (b & 7) * 125 + (b >> 3);   // XCD-contiguous remap
        const int gid = chunk * 256 + tid;
        const int e = gid >> 4;
        const int L = gid & 15;
        const float* uSo = Sbuf + t * 32000;
        float* uSn = Sbuf + (t + 1) * 32000;
        const int i = edges[2 * e], j = edges[2 * e + 1];
        const float mold_ij = msg[(NE + e) * 16 + L];   // into i
        const float mold_ji = msg[e * 16 + L];          // into j
        const float bi = uSo[i * 16 + L] - mold_ij;
        const float bj = uSo[j * 16 + L] - mold_ji;
        const float4* pt = (const float4*)(pT + e * 256 + L * 16);  // pT[e][L][*] = p[e][*][L]
        const float4 q0 = pt[0], q1 = pt[1], q2 = pt[2], q3 = pt[3];
        float pv[16] = {q0.x, q0.y, q0.z, q0.w, q1.x, q1.y, q1.z, q1.w,
                        q2.x, q2.y, q2.z, q2.w, q3.x, q3.y, q3.z, q3.w};
        float mj = -INFINITY, vmax = -INFINITY;
        #pragma unroll
        for (int a = 0; a < 16; ++a) {
            float v = pv[a];
            float bia = __shfl(bi, a, 16);
            mj = fmaxf(mj, v + bia);
            vmax = fmaxf(vmax, v);
        }
        float mi = vmax + bj;
        float sj = mj, si = mi;
        #pragma unroll
        for (int off = 1; off < 16; off <<= 1) {
            sj += __shfl_xor(sj, off, 16);
            si += __shfl_xor(si, off, 16);
        }
        mj -= sj * (1.f / 16.f);
        mi -= si * (1.f / 16.f);
        msg[e * 16 + L] = mj;
        msg[(NE + e) * 16 + L] = mi;
        if (wflag[e]) {  // only the representative of a duplicate pair feeds S
            atomicAdd(&uSn[j * 16 + L], mj);
            atomicAdd(&uSn[i * 16 + L], mi);
        }
    } else if (t > 0) {
        // ---- node phase, iter t-1 (uS[t] complete as of previous launch) ----
        const int r = (blockIdx.x - 1000) * 256 + tid;
        const float* Sn = Sbuf + t * 32000;    // = u + S[t]
        float partial = 0.f;
        if (r < N_NODES) {
            int n = r;
            float bv = Sn[n * 16];
            int best = 0;
            #pragma unroll
            for (int a = 1; a < 16; ++a) {
                float v = Sn[n * 16 + a];
                if (v > bv) { bv = v; best = a; }
            }
            aidx[(t - 1) * N_NODES + n] = best;
            partial = u[n * 16 + best];
        } else if (r < N_NODES + NE) {
            int ee = r - N_NODES;
            int ii = edges[2 * ee], jj = edges[2 * ee + 1];
            float bvi = Sn[ii * 16]; int ai = 0;
            #pragma unroll
            for (int a = 1; a < 16; ++a) {
                float v = Sn[ii * 16 + a];
                if (v > bvi) { bvi = v; ai = a; }
            }
            float bvj = Sn[jj * 16]; int aj = 0;
            #pragma unroll
            for (int a = 1; a < 16; ++a) {
                float v = Sn[jj * 16 + a];
                if (v > bvj) { bvj = v; aj = a; }
            }
            partial = p[ee * 256 + ai * 16 + aj];
        }
        #pragma unroll
        for (int off = 1; off < 64; off <<= 1) partial += __shfl_xor(partial, off, 64);
        if ((tid & 63) == 0) atomicAdd(&q[t - 1], partial);
    }
}

// ---------------- tail node phase for the last iteration (t = NITERS-1) -----
__global__ __launch_bounds__(256) void mp_tail_kernel(
    const float* __restrict__ u, const float* __restrict__ Sbuf,
    const float* __restrict__ p, const int* __restrict__ edges,
    int* __restrict__ aidx, float* __restrict__ q)
{
    const int tid = threadIdx.x;
    const int r = blockIdx.x * 256 + tid;
    const float* Sn = Sbuf + NITERS * 32000;   // = u + S[8]
    float partial = 0.f;
    if (r < N_NODES) {
        int n = r;
        float bv = Sn[n * 16];
        int best = 0;
        #pragma unroll
        for (int a = 1; a < 16; ++a) {
            float v = Sn[n * 16 + a];
            if (v > bv) { bv = v; best = a; }
        }
        aidx[(NITERS - 1) * N_NODES + n] = best;
        partial = u[n * 16 + best];
    } else if (r < N_NODES + NE) {
        int ee = r - N_NODES;
        int ii = edges[2 * ee], jj = edges[2 * ee + 1];
        float bvi = Sn[ii * 16]; int ai = 0;
        #pragma unroll
        for (int a = 1; a < 16; ++a) {
            float v = Sn[ii * 16 + a];
            if (v > bvi) { bvi = v; ai = a; }
        }
        float bvj = Sn[jj * 16]; int aj = 0;
        #pragma unroll
        for (int a = 1; a < 16; ++a) {
            float v = Sn[jj * 16 + a];
            if (v > bvj) { bvj = v; aj = a; }
        }
        partial = p[ee * 256 + ai * 16 + aj];
    }
    #pragma unroll
    for (int off = 1; off < 64; off <<= 1) partial += __shfl_xor(partial, off, 64);
    if ((tid & 63) == 0) atomicAdd(&q[NITERS - 1], partial);
}

// ---------------- final: running strict-> max over iters, one-hot a ---------
__global__ __launch_bounds__(256) void final_kernel(
    const float* __restrict__ q, const int* __restrict__ aidx,
    float* __restrict__ a_out, float* __restrict__ q_out)
{
    int id = blockIdx.x * 256 + threadIdx.x;
    float cur = 0.f; int best_t = -1;
    #pragma unroll
    for (int t = 0; t < NITERS; ++t) {
        float qv = q[t];
        if (qv > cur) { cur = qv; best_t = t; }
    }
    if (id < N_NODES * 16) {
        int n = id >> 4, c = id & 15;
        float val = 0.f;
        if (best_t >= 0 && aidx[best_t * N_NODES + n] == c) val = 1.f;
        a_out[id] = val;
        if (id == 0) q_out[0] = cur;
    }
}

extern "C" void kernel_launch(void* const* d_in, const int* in_sizes, int n_in,
                              void* d_out, int out_size, void* d_ws, size_t ws_size,
                              hipStream_t stream)
{
    (void)in_sizes; (void)n_in; (void)out_size; (void)ws_size;
    const float* x    = (const float*)d_in[0];
    const float* pa   = (const float*)d_in[1];
    const float* st   = (const float*)d_in[2];
    const int*   edges= (const int*)d_in[3];
    const float* gwih = (const float*)d_in[4];
    const float* gwhh = (const float*)d_in[5];
    const float* gbih = (const float*)d_in[6];
    const float* gbhh = (const float*)d_in[7];
    const float* uW0 = (const float*)d_in[8];  const float* ub0 = (const float*)d_in[9];
    const float* uW1 = (const float*)d_in[10]; const float* ub1 = (const float*)d_in[11];
    const float* uW2 = (const float*)d_in[12]; const float* ub2 = (const float*)d_in[13];
    const float* pW0 = (const float*)d_in[14]; const float* pb0 = (const float*)d_in[15];
    const float* pW1 = (const float*)d_in[16]; const float* pb1 = (const float*)d_in[17];
    const float* pW2 = (const float*)d_in[18]; const float* pb2 = (const float*)d_in[19];
    const float* pW3 = (const float*)d_in[20]; const float* pb3 = (const float*)d_in[21];
    const float* pW4 = (const float*)d_in[22]; const float* pb4 = (const float*)d_in[23];

    float* out   = (float*)d_out;
    float* a_out = out;                 // 32000
    float* q_out = out + 32000;         // 1
    float* u_out = out + 32001;         // 32000
    float* p_out = out + 64001;         // 4,096,000
    float* h_out = out + 4160001;       // 256,000 (state_out)

    float* ws   = (float*)d_ws;
    float* msg  = ws + WS_MSG;
    float* Sbuf = ws + WS_SBUF;         // uS ring: slot t = u + S[t]
    float* q    = ws + WS_Q;
    int*   aidx = (int*)(ws + WS_AIDX);
    int*   wfl  = (int*)(ws + WS_W);
    float* pT   = ws + WS_PT;
    float* cab  = ws + WS_CAB;
    int*   owner= (int*)(ws + WS_PT);   // aliases pT; dead before pmlp runs

    setup_kernel<<<1024, 256, 0, stream>>>(ws, uW0, uW1, uW2, pW0, pW1, pW2, pW3, pW4,
                                           gwih, gwhh);
    init_owner_kernel<<<(NE + 255) / 256, 256, 0, stream>>>(edges, owner);
    claim_kernel<<<(NE + 255) / 256, 256, 0, stream>>>(edges, owner);
    resolve_kernel<<<(NE + 255) / 256, 256, 0, stream>>>(edges, owner, wfl);
    gru_kernel<<<N_NODES / 8, 256, 0, stream>>>(x, pa, st, ws + WS_GIT, ws + WS_GHT,
                                                gbih, gbhh, h_out);
    umlp_kernel<<<500, 256, 0, stream>>>(h_out, ws + WS_UW0T, ub0,
                                         ws + WS_UW1T, ub1, ws + WS_UW2T, ub2,
                                         ws + WS_UWCAT, u_out, Sbuf, cab);
    pmlp_kernel<<<NE / 16, 256, 0, stream>>>(cab, edges, pb0,
                                             ws + WS_PW1T, pb1,
                                             ws + WS_PW2T, pb2, ws + WS_PW3T, pb3,
                                             ws + WS_PW4T, pb4, p_out, pT);
    for (int t = 0; t < NITERS; ++t) {
        mp_iter_kernel<<<1071, 256, 0, stream>>>(u_out, Sbuf, msg, pT, p_out,
                                                 edges, wfl, aidx, q, t);
    }
    mp_tail_kernel<<<71, 256, 0, stream>>>(u_out, Sbuf, p_out, edges, aidx, q);
    final_kernel<<<125, 256, 0, stream>>>(q, aidx, a_out, q_out);
}

// Round 12
// 332.487 us; speedup vs baseline: 1.0261x; 1.0261x over previous
//
#include <hip/hip_runtime.h>
#include <math.h>

#define N_NODES 2000
#define NA 16
#define NOBS 64
#define NH 128
#define NE 16000
#define NITERS 8

// ---------------- workspace layout (float offsets) ----------------
#define WS_MSG       0                       // 2E*16 = 512000
#define WS_Q         512000                  // 8
#define WS_ZERO_CNT  512008                  // msg + q zeroed in setup
#define WS_SBUF      512016                  // 9 x 32000 uS buffers (u-initialized by umlp)
#define WS_AIDX      800016                  // int[8*2000]
#define WS_W         816016                  // int[16000] wflag
#define WS_PT        832016                  // pT 4,096,000; owner map (4,000,000 ints) aliases
#define WS_GIT       (WS_PT + 4000000)       // gru wihT k-panel 80x384 = 30720 (dead after gru)
#define WS_GHT       (WS_GIT + 30720)        // gru whhT k-panel 128x384 = 49152 (ends < WS_WB)
#define WS_WB        4928016                 // transposed weights base (contiguous chain)
#define WS_UW0T      (WS_WB + 0)             // 128x256
#define WS_UWCAT     (WS_WB + 32768)         // 128x256  [W0a@h | W0b@h] combined
#define WS_UW1T      (WS_WB + 65536)         // 256x256
#define WS_UW2T      (WS_WB + 131072)        // 256x16
#define WS_PW1T      (WS_WB + 135168)        // 128x256
#define WS_PW2T      (WS_WB + 167936)        // 256x256
#define WS_PW3T      (WS_WB + 233472)        // 256x16
#define WS_PW4T      (WS_WB + 237568)        // 16x256
#define WS_CAB       (WS_WB + 241664)        // cab[2000][256] = 512000
// end: 5,681,680 floats (~22.7 MB)
// NOTE: weight ping-pong prefetch reads up to ~2K floats past an array's
// end — always lands in the NEXT array in the chain (benign).

// ---------------- setup (blocks 0..1023) + init_owner (1024..1086) -----------
__global__ __launch_bounds__(256) void setup_kernel(
    float* __restrict__ ws, const int* __restrict__ edges,
    const float* __restrict__ uW0, const float* __restrict__ uW1,
    const float* __restrict__ uW2, const float* __restrict__ pW0,
    const float* __restrict__ pW1, const float* __restrict__ pW2,
    const float* __restrict__ pW3, const float* __restrict__ pW4,
    const float* __restrict__ gwih, const float* __restrict__ gwhh)
{
    if (blockIdx.x >= 1024) {
        int e = (blockIdx.x - 1024) * 256 + threadIdx.x;
        if (e < NE) {
            int i = edges[2 * e], j = edges[2 * e + 1];
            ((int*)(ws + WS_PT))[i * N_NODES + j] = -1;
        }
        return;
    }
    const int total = WS_ZERO_CNT + 321536;
    for (int idx = blockIdx.x * 256 + threadIdx.x; idx < total;
         idx += 1024 * 256) {
        if (idx < WS_ZERO_CNT) {
            ws[idx] = 0.f;
        } else {
            int t = idx - WS_ZERO_CNT;
            if (t < 241664) {
                float v;
                if (t < 32768) {
                    int k = t / 256, o = t % 256;           // uW0T
                    v = uW0[o * 128 + k];
                } else if (t < 65536) {
                    int q = t - 32768, k = q / 256, o = q % 256;  // UWCAT: split pW0
                    v = (o < 128) ? pW0[o * 256 + k]
                                  : pW0[(o - 128) * 256 + 128 + k];
                } else if (t < 131072) {
                    int q = t - 65536, k = q / 256, o = q % 256;  // uW1T
                    v = uW1[o * 256 + k];
                } else if (t < 135168) {
                    int q = t - 131072, k = q / 16, o = q % 16;   // uW2T
                    v = uW2[o * 256 + k];
                } else if (t < 167936) {
                    int q = t - 135168, k = q / 256, o = q % 256; // pW1T
                    v = pW1[o * 128 + k];
                } else if (t < 233472) {
                    int q = t - 167936, k = q / 256, o = q % 256; // pW2T
                    v = pW2[o * 256 + k];
                } else if (t < 237568) {
                    int q = t - 233472, k = q / 16, o = q % 16;   // pW3T
                    v = pW3[o * 256 + k];
                } else {
                    int q = t - 237568, k = q / 256, o = q % 256; // pW4T
                    v = pW4[o * 16 + k];
                }
                ws[WS_WB + t] = v;
            } else if (t < 272384) {
                int q = t - 241664;   // gru wihT k-panel
                int k4 = q / 1536, r = q % 1536, g = r >> 2, c = r & 3;
                ws[WS_GIT + q] = gwih[g * 80 + 4 * k4 + c];
            } else {
                int q = t - 272384;
                int k4 = q / 1536, r = q % 1536, g = r >> 2, c = r & 3;
                ws[WS_GHT + q] = gwhh[g * 128 + 4 * k4 + c];
            }
        }
    }
}

// ---------------- GRU (blocks 0..249) + claim (250..312) ---------------------
__global__ __launch_bounds__(256) void gru_kernel(
    const float* __restrict__ x, const float* __restrict__ pa,
    const float* __restrict__ st, const float* __restrict__ wihT,
    const float* __restrict__ whhT, const float* __restrict__ bih,
    const float* __restrict__ bhh, float* __restrict__ h_out,
    const int* __restrict__ edges, int* __restrict__ owner)
{
    if (blockIdx.x >= 250) {
        int e = (blockIdx.x - 250) * 256 + threadIdx.x;
        if (e < NE) {
            int i = edges[2 * e], j = edges[2 * e + 1];
            atomicMax(&owner[i * N_NODES + j], e);
        }
        return;
    }
    __shared__ float enc[8][80];
    __shared__ float hp[8][128];
    __shared__ float gi[8][384];
    __shared__ float gh[8][384];
    const int tid = threadIdx.x;
    const int n0 = blockIdx.x * 8;

    for (int idx = tid; idx < 8 * 80; idx += 256) {
        int r = idx / 80, c = idx % 80;
        enc[r][c] = (c < 64) ? x[(n0 + r) * 64 + c] : pa[(n0 + r) * 16 + (c - 64)];
    }
    for (int idx = tid; idx < 8 * 128; idx += 256) {
        int r = idx >> 7, c = idx & 127;
        hp[r][c] = st[(n0 + r) * 128 + c];
    }
    __syncthreads();

    for (int idx = tid; idx < 8 * 384; idx += 256) {
        int g = idx % 384, r = idx / 384;
        float s1 = bih[g];
        #pragma unroll 5
        for (int k4 = 0; k4 < 20; ++k4) {
            const float4 ev = *(const float4*)&enc[r][4 * k4];
            const float4 wv = *(const float4*)&wihT[k4 * 1536 + g * 4];
            s1 = fmaf(ev.x, wv.x, fmaf(ev.y, wv.y, fmaf(ev.z, wv.z, fmaf(ev.w, wv.w, s1))));
        }
        gi[r][g] = s1;
        float s2 = bhh[g];
        #pragma unroll 8
        for (int k4 = 0; k4 < 32; ++k4) {
            const float4 hv = *(const float4*)&hp[r][4 * k4];
            const float4 wv = *(const float4*)&whhT[k4 * 1536 + g * 4];
            s2 = fmaf(hv.x, wv.x, fmaf(hv.y, wv.y, fmaf(hv.z, wv.z, fmaf(hv.w, wv.w, s2))));
        }
        gh[r][g] = s2;
    }
    __syncthreads();

    for (int idx = tid; idx < 8 * 128; idx += 256) {
        int r = idx >> 7, c = idx & 127;
        float rr = 1.f / (1.f + expf(-(gi[r][c] + gh[r][c])));
        float zz = 1.f / (1.f + expf(-(gi[r][128 + c] + gh[r][128 + c])));
        float nn = tanhf(gi[r][256 + c] + rr * gh[r][256 + c]);
        h_out[(n0 + r) * 128 + c] = (1.f - zz) * nn + zz * hp[r][c];
    }
}

// ---------------- u MLP (0..249) + cab (250..499) + resolve (500..562) -------
__global__ __launch_bounds__(256) void umlp_kernel(
    const float* __restrict__ h, const float* __restrict__ w0t,
    const float* __restrict__ b0, const float* __restrict__ w1t,
    const float* __restrict__ b1, const float* __restrict__ w2t,
    const float* __restrict__ b2, const float* __restrict__ wcat,
    float* __restrict__ u_out, float* __restrict__ Sbuf,
    float* __restrict__ cab, const int* __restrict__ edges,
    const int* __restrict__ owner, int* __restrict__ wflag)
{
    if (blockIdx.x >= 500) {
        int e = (blockIdx.x - 500) * 256 + threadIdx.x;
        if (e < NE) {
            int i = edges[2 * e], j = edges[2 * e + 1];
            wflag[e] = (owner[i * N_NODES + j] == e) ? 1 : 0;
        }
        return;
    }
    __shared__ float A[8][128];
    __shared__ float B[8][256];
    const int tid = threadIdx.x;
    const bool is_cab = blockIdx.x >= 250;
    const int n0 = (is_cab ? blockIdx.x - 250 : blockIdx.x) * 8;

    for (int idx = tid; idx < 8 * 128; idx += 256) {
        int r = idx >> 7, c = idx & 127;
        A[r][c] = h[(n0 + r) * 128 + c];
    }
    __syncthreads();

    if (is_cab) {
        // 128->256, no bias/relu, ping-pong weights
        const int o = tid;
        const float* wp = wcat + o;
        float wA[4], wB[4];
        #pragma unroll
        for (int c = 0; c < 4; ++c) wA[c] = wp[c * 256];
        float acc[8];
        #pragma unroll
        for (int r = 0; r < 8; ++r) acc[r] = 0.f;
        for (int k4 = 0; k4 < 32; k4 += 2) {
            #pragma unroll
            for (int c = 0; c < 4; ++c) wB[c] = wp[(4 * (k4 + 1) + c) * 256];
            #pragma unroll
            for (int r = 0; r < 8; ++r) {
                const float4 av = *(const float4*)&A[r][4 * k4];
                acc[r] = fmaf(av.x, wA[0], fmaf(av.y, wA[1], fmaf(av.z, wA[2], fmaf(av.w, wA[3], acc[r]))));
            }
            #pragma unroll
            for (int c = 0; c < 4; ++c) wA[c] = wp[(4 * (k4 + 2) + c) * 256]; // benign OOB at last pair
            #pragma unroll
            for (int r = 0; r < 8; ++r) {
                const float4 av = *(const float4*)&A[r][4 * k4 + 4];
                acc[r] = fmaf(av.x, wB[0], fmaf(av.y, wB[1], fmaf(av.z, wB[2], fmaf(av.w, wB[3], acc[r]))));
            }
        }
        #pragma unroll
        for (int r = 0; r < 8; ++r) cab[(n0 + r) * 256 + o] = acc[r];
        return;
    }

    // L0: 128->256 relu, A->B
    {
        const int o = tid;
        const float* wp = w0t + o;
        float wA[4], wB[4];
        #pragma unroll
        for (int c = 0; c < 4; ++c) wA[c] = wp[c * 256];
        float acc[8];
        #pragma unroll
        for (int r = 0; r < 8; ++r) acc[r] = b0[o];
        for (int k4 = 0; k4 < 32; k4 += 2) {
            #pragma unroll
            for (int c = 0; c < 4; ++c) wB[c] = wp[(4 * (k4 + 1) + c) * 256];
            #pragma unroll
            for (int r = 0; r < 8; ++r) {
                const float4 av = *(const float4*)&A[r][4 * k4];
                acc[r] = fmaf(av.x, wA[0], fmaf(av.y, wA[1], fmaf(av.z, wA[2], fmaf(av.w, wA[3], acc[r]))));
            }
            #pragma unroll
            for (int c = 0; c < 4; ++c) wA[c] = wp[(4 * (k4 + 2) + c) * 256]; // benign OOB at last pair
            #pragma unroll
            for (int r = 0; r < 8; ++r) {
                const float4 av = *(const float4*)&A[r][4 * k4 + 4];
                acc[r] = fmaf(av.x, wB[0], fmaf(av.y, wB[1], fmaf(av.z, wB[2], fmaf(av.w, wB[3], acc[r]))));
            }
        }
        #pragma unroll
        for (int r = 0; r < 8; ++r) B[r][o] = fmaxf(acc[r], 0.f);
    }
    __syncthreads();
    // L1: 256->256 relu, B->B (register staged)
    {
        const int o = tid;
        const float* wp = w1t + o;
        float wA[4], wB[4];
        #pragma unroll
        for (int c = 0; c < 4; ++c) wA[c] = wp[c * 256];
        float acc[8];
        #pragma unroll
        for (int r = 0; r < 8; ++r) acc[r] = b1[o];
        for (int k4 = 0; k4 < 64; k4 += 2) {
            #pragma unroll
            for (int c = 0; c < 4; ++c) wB[c] = wp[(4 * (k4 + 1) + c) * 256];
            #pragma unroll
            for (int r = 0; r < 8; ++r) {
                const float4 av = *(const float4*)&B[r][4 * k4];
                acc[r] = fmaf(av.x, wA[0], fmaf(av.y, wA[1], fmaf(av.z, wA[2], fmaf(av.w, wA[3], acc[r]))));
            }
            #pragma unroll
            for (int c = 0; c < 4; ++c) wA[c] = wp[(4 * (k4 + 2) + c) * 256]; // benign OOB at last pair
            #pragma unroll
            for (int r = 0; r < 8; ++r) {
                const float4 av = *(const float4*)&B[r][4 * k4 + 4];
                acc[r] = fmaf(av.x, wB[0], fmaf(av.y, wB[1], fmaf(av.z, wB[2], fmaf(av.w, wB[3], acc[r]))));
            }
        }
        __syncthreads();
        #pragma unroll
        for (int r = 0; r < 8; ++r) B[r][o] = fmaxf(acc[r], 0.f);
    }
    __syncthreads();
    // L2: 256->16, /N, no relu (threads 0..127); fan out to u and 9 uS slots
    if (tid < 128) {
        int r = tid >> 4, o = tid & 15;
        float acc = b2[o];
        for (int k4 = 0; k4 < 64; ++k4) {
            const float4 av = *(const float4*)&B[r][4 * k4];
            acc = fmaf(av.x, w2t[(4 * k4 + 0) * 16 + o],
                  fmaf(av.y, w2t[(4 * k4 + 1) * 16 + o],
                  fmaf(av.z, w2t[(4 * k4 + 2) * 16 + o],
                  fmaf(av.w, w2t[(4 * k4 + 3) * 16 + o], acc))));
        }
        float val = acc * (1.f / N_NODES);
        int idx = (n0 + r) * 16 + o;
        u_out[idx] = val;
        #pragma unroll
        for (int t = 0; t < NITERS + 1; ++t) Sbuf[t * 32000 + idx] = val;
    }
}

// ---------------- p MLP: L0 collapsed to cab gather + add --------------------
// 32 rows (16 edges)/block, single LDS buffer (35 KB, 4 blocks/CU).
__global__ __launch_bounds__(256, 4) void pmlp_kernel(
    const float* __restrict__ cab, const int* __restrict__ edges,
    const float* __restrict__ b0,
    const float* __restrict__ w1t, const float* __restrict__ b1,
    const float* __restrict__ w2t, const float* __restrict__ b2,
    const float* __restrict__ w3t, const float* __restrict__ b3,
    const float* __restrict__ w4t, const float* __restrict__ b4,
    float* __restrict__ p_out, float* __restrict__ pT)
{
    __shared__ float A[32][256];   // 32 KB — the only activation buffer
    __shared__ float C16[32][16];  // 2 KB
    __shared__ int fi[32], se[32];
    const int tid = threadIdx.x;
    const int e0 = blockIdx.x * 16;
    const int rg = tid >> 6;       // wave id = row group
    const int ct = tid & 63;
    const int r0 = rg * 8;

    if (tid < 16) {
        int i = edges[2 * (e0 + tid)], j = edges[2 * (e0 + tid) + 1];
        fi[2 * tid] = i;     se[2 * tid] = j;       // row 2s  = dir (i,j)
        fi[2 * tid + 1] = j; se[2 * tid + 1] = i;   // row 2s+1 = dir (j,i)
    }
    __syncthreads();
    // L0 (collapsed): A[r][0..127] = relu(ca[fi] + cb[se] + b0)
    {
        const int cl = tid & 127;
        const int rh = tid >> 7;   // 0 or 1: rows 0-15 / 16-31
        const float bb = b0[cl];
        #pragma unroll 4
        for (int r = rh * 16; r < rh * 16 + 16; ++r) {
            float v = cab[fi[r] * 256 + cl] + cab[se[r] * 256 + 128 + cl] + bb;
            A[r][cl] = fmaxf(v, 0.f);
        }
    }
    __syncthreads();
    // L1: 128->256 relu. Reads A[r][0..127], writes A[r][0..255] (4 cols/thr).
    // Rows wave-private from here; loads precede stores in wave program order.
    {
        const float4* wp = (const float4*)w1t + ct;
        float4 wA[4], wB[4];
        #pragma unroll
        for (int c = 0; c < 4; ++c) wA[c] = wp[c * 64];
        float4 bb = ((const float4*)b1)[ct];
        float acc[8][4];
        #pragma unroll
        for (int r = 0; r < 8; ++r) {
            acc[r][0] = bb.x; acc[r][1] = bb.y; acc[r][2] = bb.z; acc[r][3] = bb.w;
        }
        for (int k4 = 0; k4 < 32; k4 += 2) {
            #pragma unroll
            for (int c = 0; c < 4; ++c) wB[c] = wp[(4 * (k4 + 1) + c) * 64];
            #pragma unroll
            for (int r = 0; r < 8; ++r) {
                const float4 av = *(const float4*)&A[r0 + r][4 * k4];
                acc[r][0] = fmaf(av.x, wA[0].x, fmaf(av.y, wA[1].x, fmaf(av.z, wA[2].x, fmaf(av.w, wA[3].x, acc[r][0]))));
                acc[r][1] = fmaf(av.x, wA[0].y, fmaf(av.y, wA[1].y, fmaf(av.z, wA[2].y, fmaf(av.w, wA[3].y, acc[r][1]))));
                acc[r][2] = fmaf(av.x, wA[0].z, fmaf(av.y, wA[1].z, fmaf(av.z, wA[2].z, fmaf(av.w, wA[3].z, acc[r][2]))));
                acc[r][3] = fmaf(av.x, wA[0].w, fmaf(av.y, wA[1].w, fmaf(av.z, wA[2].w, fmaf(av.w, wA[3].w, acc[r][3]))));
            }
            #pragma unroll
            for (int c = 0; c < 4; ++c) wA[c] = wp[(4 * (k4 + 2) + c) * 64]; // benign OOB at last pair
            #pragma unroll
            for (int r = 0; r < 8; ++r) {
                const float4 av = *(const float4*)&A[r0 + r][4 * k4 + 4];
                acc[r][0] = fmaf(av.x, wB[0].x, fmaf(av.y, wB[1].x, fmaf(av.z, wB[2].x, fmaf(av.w, wB[3].x, acc[r][0]))));
                acc[r][1] = fmaf(av.x, wB[0].y, fmaf(av.y, wB[1].y, fmaf(av.z, wB[2].y, fmaf(av.w, wB[3].y, acc[r][1]))));
                acc[r][2] = fmaf(av.x, wB[0].z, fmaf(av.y, wB[1].z, fmaf(av.z, wB[2].z, fmaf(av.w, wB[3].z, acc[r][2]))));
                acc[r][3] = fmaf(av.x, wB[0].w, fmaf(av.y, wB[1].w, fmaf(av.z, wB[2].w, fmaf(av.w, wB[3].w, acc[r][3]))));
            }
        }
        #pragma unroll
        for (int r = 0; r < 8; ++r) {
            float4 v = make_float4(fmaxf(acc[r][0], 0.f), fmaxf(acc[r][1], 0.f),
                                   fmaxf(acc[r][2], 0.f), fmaxf(acc[r][3], 0.f));
            *(float4*)&A[r0 + r][4 * ct] = v;
        }
    }
    // no __syncthreads — rows wave-private
    // L2: 256->256 relu, in place (4 cols/thread).
    {
        const float4* wp = (const float4*)w2t + ct;
        float4 wA[4], wB[4];
        #pragma unroll
        for (int c = 0; c < 4; ++c) wA[c] = wp[c * 64];
        float4 bb = ((const float4*)b2)[ct];
        float acc[8][4];
        #pragma unroll
        for (int r = 0; r < 8; ++r) {
            acc[r][0] = bb.x; acc[r][1] = bb.y; acc[r][2] = bb.z; acc[r][3] = bb.w;
        }
        for (int k4 = 0; k4 < 64; k4 += 2) {
            #pragma unroll
            for (int c = 0; c < 4; ++c) wB[c] = wp[(4 * (k4 + 1) + c) * 64];
            #pragma unroll
            for (int r = 0; r < 8; ++r) {
                const float4 av = *(const float4*)&A[r0 + r][4 * k4];
                acc[r][0] = fmaf(av.x, wA[0].x, fmaf(av.y, wA[1].x, fmaf(av.z, wA[2].x, fmaf(av.w, wA[3].x, acc[r][0]))));
                acc[r][1] = fmaf(av.x, wA[0].y, fmaf(av.y, wA[1].y, fmaf(av.z, wA[2].y, fmaf(av.w, wA[3].y, acc[r][1]))));
                acc[r][2] = fmaf(av.x, wA[0].z, fmaf(av.y, wA[1].z, fmaf(av.z, wA[2].z, fmaf(av.w, wA[3].z, acc[r][2]))));
                acc[r][3] = fmaf(av.x, wA[0].w, fmaf(av.y, wA[1].w, fmaf(av.z, wA[2].w, fmaf(av.w, wA[3].w, acc[r][3]))));
            }
            #pragma unroll
            for (int c = 0; c < 4; ++c) wA[c] = wp[(4 * (k4 + 2) + c) * 64]; // benign OOB at last pair
            #pragma unroll
            for (int r = 0; r < 8; ++r) {
                const float4 av = *(const float4*)&A[r0 + r][4 * k4 + 4];
                acc[r][0] = fmaf(av.x, wB[0].x, fmaf(av.y, wB[1].x, fmaf(av.z, wB[2].x, fmaf(av.w, wB[3].x, acc[r][0]))));
                acc[r][1] = fmaf(av.x, wB[0].y, fmaf(av.y, wB[1].y, fmaf(av.z, wB[2].y, fmaf(av.w, wB[3].y, acc[r][1]))));
                acc[r][2] = fmaf(av.x, wB[0].z, fmaf(av.y, wB[1].z, fmaf(av.z, wB[2].z, fmaf(av.w, wB[3].z, acc[r][2]))));
                acc[r][3] = fmaf(av.x, wB[0].w, fmaf(av.y, wB[1].w, fmaf(av.z, wB[2].w, fmaf(av.w, wB[3].w, acc[r][3]))));
            }
        }
        #pragma unroll
        for (int r = 0; r < 8; ++r) {
            float4 v = make_float4(fmaxf(acc[r][0], 0.f), fmaxf(acc[r][1], 0.f),
                                   fmaxf(acc[r][2], 0.f), fmaxf(acc[r][3], 0.f));
            *(float4*)&A[r0 + r][4 * ct] = v;
        }
    }
    __syncthreads();   // L3 crosses waves
    // L3: 256->16 relu, A->C16   (512 tasks)
    for (int idx = tid; idx < 512; idx += 256) {
        int r = idx >> 4, o = idx & 15;
        float acc = b3[o];
        for (int k4 = 0; k4 < 64; ++k4) {
            const float4 av = *(const float4*)&A[r][4 * k4];
            acc = fmaf(av.x, w3t[(4 * k4 + 0) * 16 + o],
                  fmaf(av.y, w3t[(4 * k4 + 1) * 16 + o],
                  fmaf(av.z, w3t[(4 * k4 + 2) * 16 + o],
                  fmaf(av.w, w3t[(4 * k4 + 3) * 16 + o], acc))));
        }
        C16[r][o] = fmaxf(acc, 0.f);
    }
    __syncthreads();
    // L4: 16->256 (no relu), combine dirs, /E ; write p and pT
    {
        int o = tid;
        int ai = o >> 4, aj = o & 15;
        float acc[32];
        #pragma unroll
        for (int r = 0; r < 32; ++r) acc[r] = b4[o];
        #pragma unroll
        for (int k4 = 0; k4 < 4; ++k4) {
            float w0v = w4t[(4 * k4 + 0) * 256 + o];
            float w1v = w4t[(4 * k4 + 1) * 256 + o];
            float w2v = w4t[(4 * k4 + 2) * 256 + o];
            float w3v = w4t[(4 * k4 + 3) * 256 + o];
            #pragma unroll
            for (int r = 0; r < 32; ++r) {
                const float4 av = *(const float4*)&C16[r][4 * k4];
                acc[r] = fmaf(av.x, w0v, fmaf(av.y, w1v, fmaf(av.z, w2v, fmaf(av.w, w3v, acc[r]))));
            }
        }
        #pragma unroll
        for (int s = 0; s < 16; ++s) {
            float v = 0.5f * (acc[2 * s] + acc[2 * s + 1]) * (1.f / NE);
            p_out[(e0 + s) * 256 + o] = v;
            pT[(e0 + s) * 256 + aj * 16 + ai] = v;   // pT[e][aj][ai]
        }
    }
}

// ---------------- merged MP iteration kernel ---------------------------------
// blocks 0..499:   edge phase iter t — each 16-lane group handles TWO edges
//                  (g, g+8000) interleaved for memory-level parallelism.
// blocks 500..570: node phase iter t-1 (uS[t] complete from prev launch).
__global__ __launch_bounds__(256) void mp_iter_kernel(
    const float* __restrict__ u, float* __restrict__ Sbuf,
    float* __restrict__ msg, const float* __restrict__ pT,
    const float* __restrict__ p, const int* __restrict__ edges,
    const int* __restrict__ wflag, int* __restrict__ aidx,
    float* __restrict__ q, int t)
{
    const int tid = threadIdx.x;
    if (blockIdx.x < 500) {
        // ---- edge phase, iter t: edges eA = g, eB = g + 8000 ----
        const int g = blockIdx.x * 16 + (tid >> 4);
        const int L = tid & 15;
        const int eA = g, eB = g + 8000;
        const float* uSo = Sbuf + t * 32000;
        float* uSn = Sbuf + (t + 1) * 32000;
        const int iA = edges[2 * eA], jA = edges[2 * eA + 1];
        const int iB = edges[2 * eB], jB = edges[2 * eB + 1];
        const float moldA_ij = msg[(NE + eA) * 16 + L];
        const float moldA_ji = msg[eA * 16 + L];
        const float moldB_ij = msg[(NE + eB) * 16 + L];
        const float moldB_ji = msg[eB * 16 + L];
        const float biA = uSo[iA * 16 + L] - moldA_ij;
        const float bjA = uSo[jA * 16 + L] - moldA_ji;
        const float biB = uSo[iB * 16 + L] - moldB_ij;
        const float bjB = uSo[jB * 16 + L] - moldB_ji;
        const float4* ptA = (const float4*)(pT + eA * 256 + L * 16);
        const float4* ptB = (const float4*)(pT + eB * 256 + L * 16);
        const float4 a0 = ptA[0], a1 = ptA[1], a2 = ptA[2], a3 = ptA[3];
        const float4 c0 = ptB[0], c1 = ptB[1], c2 = ptB[2], c3 = ptB[3];
        float pvA[16] = {a0.x, a0.y, a0.z, a0.w, a1.x, a1.y, a1.z, a1.w,
                         a2.x, a2.y, a2.z, a2.w, a3.x, a3.y, a3.z, a3.w};
        float pvB[16] = {c0.x, c0.y, c0.z, c0.w, c1.x, c1.y, c1.z, c1.w,
                         c2.x, c2.y, c2.z, c2.w, c3.x, c3.y, c3.z, c3.w};
        float mjA = -INFINITY, vmaxA = -INFINITY;
        float mjB = -INFINITY, vmaxB = -INFINITY;
        #pragma unroll
        for (int a = 0; a < 16; ++a) {
            float biaA = __shfl(biA, a, 16);
            float biaB = __shfl(biB, a, 16);
            mjA = fmaxf(mjA, pvA[a] + biaA);
            vmaxA = fmaxf(vmaxA, pvA[a]);
            mjB = fmaxf(mjB, pvB[a] + biaB);
            vmaxB = fmaxf(vmaxB, pvB[a]);
        }
        float miA = vmaxA + bjA;
        float miB = vmaxB + bjB;
        float sjA = mjA, siA = miA, sjB = mjB, siB = miB;
        #pragma unroll
        for (int off = 1; off < 16; off <<= 1) {
            sjA += __shfl_xor(sjA, off, 16);
            siA += __shfl_xor(siA, off, 16);
            sjB += __shfl_xor(sjB, off, 16);
            siB += __shfl_xor(siB, off, 16);
        }
        mjA -= sjA * (1.f / 16.f);
        miA -= siA * (1.f / 16.f);
        mjB -= sjB * (1.f / 16.f);
        miB -= siB * (1.f / 16.f);
        msg[eA * 16 + L] = mjA;
        msg[(NE + eA) * 16 + L] = miA;
        msg[eB * 16 + L] = mjB;
        msg[(NE + eB) * 16 + L] = miB;
        if (wflag[eA]) {
            atomicAdd(&uSn[jA * 16 + L], mjA);
            atomicAdd(&uSn[iA * 16 + L], miA);
        }
        if (wflag[eB]) {
            atomicAdd(&uSn[jB * 16 + L], mjB);
            atomicAdd(&uSn[iB * 16 + L], miB);
        }
    } else if (t > 0) {
        // ---- node phase, iter t-1 (uS[t] complete as of previous launch) ----
        const int r = (blockIdx.x - 500) * 256 + tid;
        const float* Sn = Sbuf + t * 32000;    // = u + S[t]
        float partial = 0.f;
        if (r < N_NODES) {
            int n = r;
            float bv = Sn[n * 16];
            int best = 0;
            #pragma unroll
            for (int a = 1; a < 16; ++a) {
                float v = Sn[n * 16 + a];
                if (v > bv) { bv = v; best = a; }
            }
            aidx[(t - 1) * N_NODES + n] = best;
            partial = u[n * 16 + best];
        } else if (r < N_NODES + NE) {
            int ee = r - N_NODES;
            int ii = edges[2 * ee], jj = edges[2 * ee + 1];
            float bvi = Sn[ii * 16]; int ai = 0;
            #pragma unroll
            for (int a = 1; a < 16; ++a) {
                float v = Sn[ii * 16 + a];
                if (v > bvi) { bvi = v; ai = a; }
            }
            float bvj = Sn[jj * 16]; int aj = 0;
            #pragma unroll
            for (int a = 1; a < 16; ++a) {
                float v = Sn[jj * 16 + a];
                if (v > bvj) { bvj = v; aj = a; }
            }
            partial = p[ee * 256 + ai * 16 + aj];
        }
        #pragma unroll
        for (int off = 1; off < 64; off <<= 1) partial += __shfl_xor(partial, off, 64);
        if ((tid & 63) == 0) atomicAdd(&q[t - 1], partial);
    }
}

// ---------------- tail node phase for the last iteration (t = NITERS-1) -----
__global__ __launch_bounds__(256) void mp_tail_kernel(
    const float* __restrict__ u, const float* __restrict__ Sbuf,
    const float* __restrict__ p, const int* __restrict__ edges,
    int* __restrict__ aidx, float* __restrict__ q)
{
    const int tid = threadIdx.x;
    const int r = blockIdx.x * 256 + tid;
    const float* Sn = Sbuf + NITERS * 32000;   // = u + S[8]
    float partial = 0.f;
    if (r < N_NODES) {
        int n = r;
        float bv = Sn[n * 16];
        int best = 0;
        #pragma unroll
        for (int a = 1; a < 16; ++a) {
            float v = Sn[n * 16 + a];
            if (v > bv) { bv = v; best = a; }
        }
        aidx[(NITERS - 1) * N_NODES + n] = best;
        partial = u[n * 16 + best];
    } else if (r < N_NODES + NE) {
        int ee = r - N_NODES;
        int ii = edges[2 * ee], jj = edges[2 * ee + 1];
        float bvi = Sn[ii * 16]; int ai = 0;
        #pragma unroll
        for (int a = 1; a < 16; ++a) {
            float v = Sn[ii * 16 + a];
            if (v > bvi) { bvi = v; ai = a; }
        }
        float bvj = Sn[jj * 16]; int aj = 0;
        #pragma unroll
        for (int a = 1; a < 16; ++a) {
            float v = Sn[jj * 16 + a];
            if (v > bvj) { bvj = v; aj = a; }
        }
        partial = p[ee * 256 + ai * 16 + aj];
    }
    #pragma unroll
    for (int off = 1; off < 64; off <<= 1) partial += __shfl_xor(partial, off, 64);
    if ((tid & 63) == 0) atomicAdd(&q[NITERS - 1], partial);
}

// ---------------- final: running strict-> max over iters, one-hot a ---------
__global__ __launch_bounds__(256) void final_kernel(
    const float* __restrict__ q, const int* __restrict__ aidx,
    float* __restrict__ a_out, float* __restrict__ q_out)
{
    int id = blockIdx.x * 256 + threadIdx.x;
    float cur = 0.f; int best_t = -1;
    #pragma unroll
    for (int t = 0; t < NITERS; ++t) {
        float qv = q[t];
        if (qv > cur) { cur = qv; best_t = t; }
    }
    if (id < N_NODES * 16) {
        int n = id >> 4, c = id & 15;
        float val = 0.f;
        if (best_t >= 0 && aidx[best_t * N_NODES + n] == c) val = 1.f;
        a_out[id] = val;
        if (id == 0) q_out[0] = cur;
    }
}

extern "C" void kernel_launch(void* const* d_in, const int* in_sizes, int n_in,
                              void* d_out, int out_size, void* d_ws, size_t ws_size,
                              hipStream_t stream)
{
    (void)in_sizes; (void)n_in; (void)out_size; (void)ws_size;
    const float* x    = (const float*)d_in[0];
    const float* pa   = (const float*)d_in[1];
    const float* st   = (const float*)d_in[2];
    const int*   edges= (const int*)d_in[3];
    const float* gwih = (const float*)d_in[4];
    const float* gwhh = (const float*)d_in[5];
    const float* gbih = (const float*)d_in[6];
    const float* gbhh = (const float*)d_in[7];
    const float* uW0 = (const float*)d_in[8];  const float* ub0 = (const float*)d_in[9];
    const float* uW1 = (const float*)d_in[10]; const float* ub1 = (const float*)d_in[11];
    const float* uW2 = (const float*)d_in[12]; const float* ub2 = (const float*)d_in[13];
    const float* pW0 = (const float*)d_in[14]; const float* pb0 = (const float*)d_in[15];
    const float* pW1 = (const float*)d_in[16]; const float* pb1 = (const float*)d_in[17];
    const float* pW2 = (const float*)d_in[18]; const float* pb2 = (const float*)d_in[19];
    const float* pW3 = (const float*)d_in[20]; const float* pb3 = (const float*)d_in[21];
    const float* pW4 = (const float*)d_in[22]; const float* pb4 = (const float*)d_in[23];

    float* out   = (float*)d_out;
    float* a_out = out;                 // 32000
    float* q_out = out + 32000;         // 1
    float* u_out = out + 32001;         // 32000
    float* p_out = out + 64001;         // 4,096,000
    float* h_out = out + 4160001;       // 256,000 (state_out)

    float* ws   = (float*)d_ws;
    float* msg  = ws + WS_MSG;
    float* Sbuf = ws + WS_SBUF;         // uS ring: slot t = u + S[t]
    float* q    = ws + WS_Q;
    int*   aidx = (int*)(ws + WS_AIDX);
    int*   wfl  = (int*)(ws + WS_W);
    float* pT   = ws + WS_PT;
    float* cab  = ws + WS_CAB;
    int*   owner= (int*)(ws + WS_PT);   // aliases pT; dead before pmlp runs

    // fused prefix: [setup ⊕ init_owner] -> [gru ⊕ claim] -> [umlp ⊕ cab ⊕ resolve]
    setup_kernel<<<1087, 256, 0, stream>>>(ws, edges, uW0, uW1, uW2,
                                           pW0, pW1, pW2, pW3, pW4, gwih, gwhh);
    gru_kernel<<<313, 256, 0, stream>>>(x, pa, st, ws + WS_GIT, ws + WS_GHT,
                                        gbih, gbhh, h_out, edges, owner);
    umlp_kernel<<<563, 256, 0, stream>>>(h_out, ws + WS_UW0T, ub0,
                                         ws + WS_UW1T, ub1, ws + WS_UW2T, ub2,
                                         ws + WS_UWCAT, u_out, Sbuf, cab,
                                         edges, owner, wfl);
    pmlp_kernel<<<NE / 16, 256, 0, stream>>>(cab, edges, pb0,
                                             ws + WS_PW1T, pb1,
                                             ws + WS_PW2T, pb2, ws + WS_PW3T, pb3,
                                             ws + WS_PW4T, pb4, p_out, pT);
    for (int t = 0; t < NITERS; ++t) {
        mp_iter_kernel<<<571, 256, 0, stream>>>(u_out, Sbuf, msg, pT, p_out,
                                                edges, wfl, aidx, q, t);
    }
    mp_tail_kernel<<<71, 256, 0, stream>>>(u_out, Sbuf, p_out, edges, aidx, q);
    final_kernel<<<125, 256, 0, stream>>>(q, aidx, a_out, q_out);
}